// Round 14
// baseline (918.946 us; speedup 1.0000x reference)
//
#include <hip/hip_runtime.h>

typedef unsigned short u16;
typedef __attribute__((ext_vector_type(8))) short bf16x8;
typedef __attribute__((ext_vector_type(4))) float f32x4;

#define DD 1024
#define TT 1024
#define NHH 16
#define VV 32000
#define FFF 4096
#define LL 4
#define MM 2048   // B*T
#define TD3 3072

__device__ __forceinline__ u16 f2bfu(float f) {
  unsigned int x = __builtin_bit_cast(unsigned int, f);
  return (u16)((x + 0x7FFFu + ((x >> 16) & 1u)) >> 16);
}

__device__ __forceinline__ void gl16(const u16* g, u16* l) {
  __builtin_amdgcn_global_load_lds((const __attribute__((address_space(1))) void*)g,
                                   (__attribute__((address_space(3))) void*)l, 16, 0, 0);
}

template <int N>
__device__ __forceinline__ void vwait() {
  if constexpr (N == 0) asm volatile("s_waitcnt vmcnt(0)" ::: "memory");
  else if constexpr (N == 4) asm volatile("s_waitcnt vmcnt(4)" ::: "memory");
  else asm volatile("s_waitcnt vmcnt(6)" ::: "memory");
}

// ------- weight transpose + f32->bf16 (16B vectorized stores) -------
__global__ void transpose_cvt_k(const float* __restrict__ in, u16* __restrict__ out,
                                int K, int N) {
  const size_t mat = (size_t)K * N;
  in += (size_t)blockIdx.z * mat;
  out += (size_t)blockIdx.z * mat;
  __shared__ float tile[32][65];
  const int n0 = blockIdx.x << 6, k0 = blockIdx.y << 5;
  const int tx = threadIdx.x, ty = threadIdx.y;
#pragma unroll
  for (int i = 0; i < 8; ++i)
    tile[(ty << 3) + i][tx] = in[(size_t)(k0 + (ty << 3) + i) * N + n0 + tx];
  __syncthreads();
  const int tid = (ty << 6) + tx;
  const int n = tid >> 2, oct = (tid & 3) << 3;
  union { u16 s[8]; uint4 u[1]; } tmp;
#pragma unroll
  for (int j = 0; j < 8; ++j) tmp.s[j] = f2bfu(tile[oct + j][n]);
  *(uint4*)(out + (size_t)(n0 + n) * K + k0 + oct) = tmp.u[0];
}

// ---------------- f32 -> bf16 elementwise (vec4) ----------------
__global__ void cvt_bf16_k(const float* __restrict__ in, u16* __restrict__ out, long n4) {
  const long i = (long)blockIdx.x * blockDim.x + threadIdx.x;
  if (i >= n4) return;
  const float4 v = ((const float4*)in)[i];
  ushort4 o;
  o.x = f2bfu(v.x); o.y = f2bfu(v.y); o.z = f2bfu(v.z); o.w = f2bfu(v.w);
  ((ushort4*)out)[i] = o;
}

// ---------------- embedding + positional ----------------
__global__ void embed_k(const int* __restrict__ tok, const float* __restrict__ emb,
                        const float* __restrict__ pos, float* __restrict__ x) {
  const int m = blockIdx.x, tid = threadIdx.x;
  const int t = m & (TT - 1);
  const int id = tok[m];
  const float4 e = ((const float4*)(emb + (size_t)id * DD))[tid];
  const float4 p = ((const float4*)(pos + (size_t)t * DD))[tid];
  float4 r;
  r.x = e.x + p.x; r.y = e.y + p.y; r.z = e.z + p.z; r.w = e.w + p.w;
  ((float4*)(x + (size_t)m * DD))[tid] = r;
}

// ---------------- RMSNorm (f32 in -> bf16 out) ----------------
__global__ void rmsnorm_k(const float* __restrict__ x, const float* __restrict__ g,
                          const float* __restrict__ be, u16* __restrict__ out) {
  const int row = blockIdx.x, tid = threadIdx.x;
  const float4 xv = ((const float4*)(x + (size_t)row * DD))[tid];
  float ss = xv.x * xv.x + xv.y * xv.y + xv.z * xv.z + xv.w * xv.w;
#pragma unroll
  for (int o = 32; o; o >>= 1) ss += __shfl_xor(ss, o);
  __shared__ float sm[4];
  if ((tid & 63) == 0) sm[tid >> 6] = ss;
  __syncthreads();
  const float tot = sm[0] + sm[1] + sm[2] + sm[3];
  const float rs = rsqrtf(tot * (1.f / DD) + 1e-6f);
  const float4 gv = ((const float4*)g)[tid];
  const float4 bv = ((const float4*)be)[tid];
  ushort4 o4;
  o4.x = f2bfu(xv.x * rs * gv.x + bv.x);
  o4.y = f2bfu(xv.y * rs * gv.y + bv.y);
  o4.z = f2bfu(xv.z * rs * gv.z + bv.z);
  o4.w = f2bfu(xv.w * rs * gv.w + bv.w);
  ((ushort4*)(out + (size_t)row * DD))[tid] = o4;
}

// ------- fused: x += sum(partials)+bias, then RMSNorm(x) -> bf16 out -------
template <int NP>
__global__ void addres_rms_k(float* __restrict__ x, const float* __restrict__ pp,
                             const float* __restrict__ bias, const float* __restrict__ g,
                             const float* __restrict__ be, u16* __restrict__ out) {
  const int row = blockIdx.x, tid = threadIdx.x;
  const size_t base = (size_t)row * (DD / 4) + tid;
  float4 s = ((float4*)x)[base];
  const float4 bv = ((const float4*)bias)[tid];
  s.x += bv.x; s.y += bv.y; s.z += bv.z; s.w += bv.w;
#pragma unroll
  for (int p = 0; p < NP; ++p) {
    const float4 pv = ((const float4*)pp)[(size_t)p * (MM * DD / 4) + base];
    s.x += pv.x; s.y += pv.y; s.z += pv.z; s.w += pv.w;
  }
  ((float4*)x)[base] = s;
  float ss = s.x * s.x + s.y * s.y + s.z * s.z + s.w * s.w;
#pragma unroll
  for (int o = 32; o; o >>= 1) ss += __shfl_xor(ss, o);
  __shared__ float sm[4];
  if ((tid & 63) == 0) sm[tid >> 6] = ss;
  __syncthreads();
  const float tot = sm[0] + sm[1] + sm[2] + sm[3];
  const float rs = rsqrtf(tot * (1.f / DD) + 1e-6f);
  const float4 gv = ((const float4*)g)[tid];
  const float4 bev = ((const float4*)be)[tid];
  ushort4 o4;
  o4.x = f2bfu(s.x * rs * gv.x + bev.x);
  o4.y = f2bfu(s.y * rs * gv.y + bev.y);
  o4.z = f2bfu(s.z * rs * gv.z + bev.z);
  o4.w = f2bfu(s.w * rs * gv.w + bev.w);
  ((ushort4*)(out + (size_t)row * DD))[tid] = o4;
}

// ======= flash attention: ONE q-tile per 4-wave block; grid 32 x 16 = 512 =======
// blocks, 56 KiB static LDS -> 2 blocks/CU. Inner loop = proven r2 flash_k.
__global__ __launch_bounds__(256) void flash4_k(const u16* __restrict__ qkv,
                                                const u16* __restrict__ Vt,
                                                u16* __restrict__ o) {
  const int z = blockIdx.x;          // b*16 + h
  const int qa = blockIdx.y;         // 0..15
  const int b = z >> 4, h = z & 15;
  const int tid = threadIdx.x;
  const int lane = tid & 63;
  const int w = tid >> 6;

  __shared__ u16 Qs[64 * 64];
  __shared__ u16 Ks[128 * 64];
  __shared__ u16 Vs[64 * 128];
  __shared__ u16 Ps[64 * 128];

  const u16* qbase = qkv + (size_t)b * TT * TD3;
  const int kcb = (lane >> 4) << 4;

  const int q0 = qa << 6;
  const int nkt = (qa >> 1) + 1;

#pragma unroll
  for (int c = 0; c < 2; ++c) {
    const int rbase = c * 32 + w * 8;
    const int row = rbase + (lane >> 3);
    const u16* src = qbase + (long)(q0 + row) * TD3 + h * 64 +
                     ((((lane & 7) << 4) ^ ((row & 7) << 4)) >> 1);
    gl16(src, &Qs[rbase * 64]);
  }

  float m_r[4], l_r[4];
  f32x4 oacc[4];
#pragma unroll
  for (int r = 0; r < 4; ++r) { m_r[r] = -1e30f; l_r[r] = 0.f; }
#pragma unroll
  for (int nd = 0; nd < 4; ++nd) oacc[nd] = (f32x4){0.f, 0.f, 0.f, 0.f};

  for (int kt = 0; kt < nkt; ++kt) {
    const int t0 = kt << 7;
#pragma unroll
    for (int c = 0; c < 4; ++c) {
      const int rbase = c * 32 + w * 8;
      const int row = rbase + (lane >> 3);
      const u16* src = qbase + (long)(t0 + row) * TD3 + DD + h * 64 +
                       ((((lane & 7) << 4) ^ ((row & 7) << 4)) >> 1);
      gl16(src, &Ks[rbase * 64]);
    }
#pragma unroll
    for (int c = 0; c < 4; ++c) {
      const int rbase = c * 16 + w * 4;
      const int d = rbase + (lane >> 4);
      const u16* src = Vt + ((long)(z * 64 + d)) * TT + t0 +
                       ((((lane & 15) << 4) ^ ((d & 7) << 4)) >> 1);
      gl16(src, &Vs[rbase * 128]);
    }
    __syncthreads();

    f32x4 sacc[8];
#pragma unroll
    for (int ni = 0; ni < 8; ++ni) sacc[ni] = (f32x4){0.f, 0.f, 0.f, 0.f};
    const int qrow = (w << 4) + (lane & 15);
#pragma unroll
    for (int ks = 0; ks < 2; ++ks) {
      const bf16x8 aq = *(const bf16x8*)&Qs[qrow * 64 + (((ks * 64 + kcb) ^ ((qrow & 7) << 4)) >> 1)];
#pragma unroll
      for (int ni = 0; ni < 8; ++ni) {
        const int key = (lane & 15) + (ni << 4);
        const bf16x8 bk = *(const bf16x8*)&Ks[key * 64 + (((ks * 64 + kcb) ^ ((key & 7) << 4)) >> 1)];
        sacc[ni] = __builtin_amdgcn_mfma_f32_16x16x32_bf16(aq, bk, sacc[ni], 0, 0, 0);
      }
    }

    float mx[4] = {-1e30f, -1e30f, -1e30f, -1e30f};
    const bool diag = (kt == nkt - 1);
#pragma unroll
    for (int ni = 0; ni < 8; ++ni)
#pragma unroll
      for (int r = 0; r < 4; ++r) {
        float v = sacc[ni][r] * 0.125f;
        if (diag) {
          const int key = t0 + (lane & 15) + (ni << 4);
          const int qq = q0 + (w << 4) + ((lane >> 4) << 2) + r;
          if (key > qq) v = -1e30f;
        }
        sacc[ni][r] = v;
        mx[r] = fmaxf(mx[r], v);
      }
#pragma unroll
    for (int st = 1; st < 16; st <<= 1)
#pragma unroll
      for (int r = 0; r < 4; ++r) mx[r] = fmaxf(mx[r], __shfl_xor(mx[r], st));
    float sc[4], sum[4];
#pragma unroll
    for (int r = 0; r < 4; ++r) {
      const float mn = fmaxf(m_r[r], mx[r]);
      sc[r] = __expf(m_r[r] - mn);
      m_r[r] = mn;
      sum[r] = 0.f;
    }
#pragma unroll
    for (int ni = 0; ni < 8; ++ni)
#pragma unroll
      for (int r = 0; r < 4; ++r) {
        const float e = __expf(sacc[ni][r] - m_r[r]);
        sum[r] += e;
        const int prow = (w << 4) + ((lane >> 4) << 2) + r;
        const int pcol = (lane & 15) + (ni << 4);
        Ps[prow * 128 + (((pcol << 1) ^ ((prow & 7) << 4)) >> 1)] = f2bfu(e);
      }
#pragma unroll
    for (int st = 1; st < 16; st <<= 1)
#pragma unroll
      for (int r = 0; r < 4; ++r) sum[r] += __shfl_xor(sum[r], st);
#pragma unroll
    for (int r = 0; r < 4; ++r) l_r[r] = l_r[r] * sc[r] + sum[r];
#pragma unroll
    for (int nd = 0; nd < 4; ++nd)
#pragma unroll
      for (int r = 0; r < 4; ++r) oacc[nd][r] *= sc[r];

#pragma unroll
    for (int ks2 = 0; ks2 < 4; ++ks2) {
      const int prow = (w << 4) + (lane & 15);
      const bf16x8 pa = *(const bf16x8*)&Ps[prow * 128 + (((ks2 * 64 + kcb) ^ ((prow & 7) << 4)) >> 1)];
#pragma unroll
      for (int nd = 0; nd < 4; ++nd) {
        const int dd2 = (lane & 15) + (nd << 4);
        const bf16x8 vb = *(const bf16x8*)&Vs[dd2 * 128 + (((ks2 * 64 + kcb) ^ ((dd2 & 7) << 4)) >> 1)];
        oacc[nd] = __builtin_amdgcn_mfma_f32_16x16x32_bf16(pa, vb, oacc[nd], 0, 0, 0);
      }
    }
    __syncthreads();
  }

  float inv[4];
#pragma unroll
  for (int r = 0; r < 4; ++r) inv[r] = 1.f / l_r[r];
#pragma unroll
  for (int nd = 0; nd < 4; ++nd)
#pragma unroll
    for (int r = 0; r < 4; ++r) {
      const int row = q0 + (w << 4) + ((lane >> 4) << 2) + r;
      const int col = (h << 6) + (lane & 15) + (nd << 4);
      o[(long)(b * TT + row) * DD + col] = f2bfu(oacc[nd][r] * inv[r]);
    }
}

// ---------------- generic batched GEMM (128^2, 2-phase; head fallback) ----------------
enum { EPI_BF16 = 0, EPI_BF16_BIAS = 1, EPI_SELU = 2, EPI_F32 = 3, EPI_RESID = 4, EPI_QKV = 5 };

template <int EPI>
__global__ __launch_bounds__(256) void gemm_bt(
    const u16* __restrict__ A, long az1, long az2, int lda,
    const u16* __restrict__ Bt, long bz1, long bz2, int ldb,
    void* __restrict__ C, long cz1, long cz2, int ldc,
    const float* __restrict__ bias, int Nvalid, int K) {
  const int z = blockIdx.z;
  A += (long)(z >> 4) * az1 + (long)(z & 15) * az2;
  Bt += (long)(z >> 4) * bz1 + (long)(z & 15) * bz2;
  const long coff = (long)(z >> 4) * cz1 + (long)(z & 15) * cz2;

  __shared__ u16 ldsA[2][128 * 32];
  __shared__ u16 ldsB[2][128 * 32];

  const int tid = threadIdx.x;
  const int lane = tid & 63;
  const int wave = tid >> 6;
  const int wr = wave >> 1, wc = wave & 1;
  const int m0 = blockIdx.x << 7, n0 = blockIdx.y << 7;

  f32x4 acc[4][4];
#pragma unroll
  for (int i = 0; i < 4; ++i)
#pragma unroll
    for (int j = 0; j < 4; ++j) acc[i][j] = (f32x4){0.f, 0.f, 0.f, 0.f};

  auto STAGE = [&](int buf, int kt) {
    const int k0 = kt << 5;
#pragma unroll
    for (int p = 0; p < 2; ++p) {
      const int c = tid + (p << 8);
      const int row = c >> 2, col = (c & 3) << 3;
      gl16(A + (long)(m0 + row) * lda + k0 + col, &ldsA[buf][c << 3]);
      gl16(Bt + (long)(n0 + row) * ldb + k0 + col, &ldsB[buf][c << 3]);
    }
  };

  const int nk = K >> 5;
  STAGE(0, 0);
  __syncthreads();
  int cur = 0;
  for (int kt = 0; kt < nk; ++kt) {
    if (kt + 1 < nk) STAGE(cur ^ 1, kt + 1);
    const int rb = lane & 15;
    const int kc = (lane >> 4) << 3;
    bf16x8 af[4], bfr[4];
#pragma unroll
    for (int mi = 0; mi < 4; ++mi)
      af[mi] = *(const bf16x8*)&ldsA[cur][(((wr << 6) + (mi << 4) + rb) << 5) + kc];
#pragma unroll
    for (int ni = 0; ni < 4; ++ni)
      bfr[ni] = *(const bf16x8*)&ldsB[cur][(((wc << 6) + (ni << 4) + rb) << 5) + kc];
#pragma unroll
    for (int mi = 0; mi < 4; ++mi)
#pragma unroll
      for (int ni = 0; ni < 4; ++ni)
        acc[mi][ni] = __builtin_amdgcn_mfma_f32_16x16x32_bf16(af[mi], bfr[ni], acc[mi][ni], 0, 0, 0);
    __syncthreads();
    cur ^= 1;
  }

  const int row0 = m0 + (wr << 6) + ((lane >> 4) << 2);
  const int col0 = n0 + (wc << 6) + (lane & 15);
#pragma unroll
  for (int ni = 0; ni < 4; ++ni) {
    const int col = col0 + (ni << 4);
    if (col >= Nvalid) continue;
    float bv = 0.f;
    if (EPI == EPI_BF16_BIAS || EPI == EPI_SELU || EPI == EPI_RESID) bv = bias[col];
#pragma unroll
    for (int mi = 0; mi < 4; ++mi) {
#pragma unroll
      for (int r = 0; r < 4; ++r) {
        const int row = row0 + (mi << 4) + r;
        const long idx = coff + (long)row * ldc + col;
        float v = acc[mi][ni][r] + bv;
        if (EPI == EPI_SELU)
          v = v > 0.f ? 1.0507009873554805f * v : 1.7580993408473766f * (__expf(v) - 1.f);
        if (EPI == EPI_BF16 || EPI == EPI_BF16_BIAS || EPI == EPI_SELU)
          ((u16*)C)[idx] = f2bfu(v);
        else if (EPI == EPI_F32)
          ((float*)C)[idx] = v;
        else
          ((float*)C)[idx] += v;
      }
    }
  }
}

// ------- gemm_bt3s: 128^2, 3-buffer ring, counted vmcnt(4), raw barriers, -------
// row-paired XOR-swizzled LDS. EPI_QKV scatters V third into Vt.
template <int EPI>
__global__ __launch_bounds__(256) void gemm_bt3s(
    const u16* __restrict__ A, long az1, long az2, int lda,
    const u16* __restrict__ Bt, long bz1, long bz2, int ldb,
    void* __restrict__ C, long cz1, long cz2, int ldc,
    const float* __restrict__ bias, int Nvalid, int K,
    u16* __restrict__ Vt) {
  const int z = blockIdx.z;
  A += (long)(z >> 4) * az1 + (long)(z & 15) * az2;
  Bt += (long)(z >> 4) * bz1 + (long)(z & 15) * bz2;
  const long coff = (long)(z >> 4) * cz1 + (long)(z & 15) * cz2;

  __shared__ u16 ldsA[3][128 * 32];
  __shared__ u16 ldsB[3][128 * 32];

  const int tid = threadIdx.x;
  const int lane = tid & 63;
  const int wave = tid >> 6;
  const int wr = wave >> 1, wc = wave & 1;
  const int m0 = blockIdx.x << 7, n0 = blockIdx.y << 7;

  f32x4 acc[4][4];
#pragma unroll
  for (int i = 0; i < 4; ++i)
#pragma unroll
    for (int j = 0; j < 4; ++j) acc[i][j] = (f32x4){0.f, 0.f, 0.f, 0.f};

  auto STAGE = [&](int buf, int kt) {
    const int k0 = kt << 5;
#pragma unroll
    for (int p = 0; p < 2; ++p) {
      const int c = tid + (p << 8);
      const int r2 = c >> 3, sp = c & 7;
      const int s = sp ^ (r2 & 7);
      const int row = r2 + ((s >> 2) << 6);
      const int col = k0 + ((s & 3) << 3);
      gl16(A + (long)(m0 + row) * lda + col, &ldsA[buf][c << 3]);
      gl16(Bt + (long)(n0 + row) * ldb + col, &ldsB[buf][c << 3]);
    }
  };

  const int nk = K >> 5;
  STAGE(0, 0);
  STAGE(1, 1);

  const int rb = lane & 15;
  const int kq = lane >> 4;
  int cur = 0, stg = 2;
#pragma unroll 1
  for (int kt = 0; kt < nk; ++kt) {
    if (kt + 1 < nk) vwait<4>();
    else vwait<0>();
    __builtin_amdgcn_s_barrier();
    __builtin_amdgcn_sched_barrier(0);

    bf16x8 af[4], bfr[4];
#pragma unroll
    for (int mi = 0; mi < 4; ++mi) {
      const int row = (wr << 6) + (mi << 4) + rb;
      const int r2 = row & 63;
      const int sp = (kq + ((row >> 6) << 2)) ^ (r2 & 7);
      af[mi] = *(const bf16x8*)&ldsA[cur][(r2 << 6) + (sp << 3)];
    }
#pragma unroll
    for (int ni = 0; ni < 4; ++ni) {
      const int row = (wc << 6) + (ni << 4) + rb;
      const int r2 = row & 63;
      const int sp = (kq + ((row >> 6) << 2)) ^ (r2 & 7);
      bfr[ni] = *(const bf16x8*)&ldsB[cur][(r2 << 6) + (sp << 3)];
    }
    asm volatile("s_waitcnt lgkmcnt(0)" ::: "memory");
    __builtin_amdgcn_sched_barrier(0);
    __builtin_amdgcn_s_barrier();
    __builtin_amdgcn_sched_barrier(0);
    if (kt + 2 < nk) STAGE(stg, kt + 2);
    __builtin_amdgcn_sched_barrier(0);

    __builtin_amdgcn_s_setprio(1);
#pragma unroll
    for (int mi = 0; mi < 4; ++mi)
#pragma unroll
      for (int ni = 0; ni < 4; ++ni)
        acc[mi][ni] = __builtin_amdgcn_mfma_f32_16x16x32_bf16(af[mi], bfr[ni], acc[mi][ni], 0, 0, 0);
    __builtin_amdgcn_s_setprio(0);

    cur = (cur == 2) ? 0 : cur + 1;
    stg = (stg == 2) ? 0 : stg + 1;
  }

  const int row0 = m0 + (wr << 6) + ((lane >> 4) << 2);
  const int col0 = n0 + (wc << 6) + (lane & 15);
#pragma unroll
  for (int ni = 0; ni < 4; ++ni) {
    const int col = col0 + (ni << 4);
    if (col >= Nvalid) continue;
    float bv = 0.f;
    if (EPI == EPI_BF16_BIAS || EPI == EPI_SELU || EPI == EPI_RESID || EPI == EPI_QKV)
      bv = bias[col];
#pragma unroll
    for (int mi = 0; mi < 4; ++mi) {
      u16 q4[4];
#pragma unroll
      for (int r = 0; r < 4; ++r) {
        const int row = row0 + (mi << 4) + r;
        const long idx = coff + (long)row * ldc + col;
        float v = acc[mi][ni][r] + bv;
        if (EPI == EPI_SELU)
          v = v > 0.f ? 1.0507009873554805f * v : 1.7580993408473766f * (__expf(v) - 1.f);
        if (EPI == EPI_BF16 || EPI == EPI_BF16_BIAS || EPI == EPI_SELU || EPI == EPI_QKV) {
          const u16 uv = f2bfu(v);
          if (EPI == EPI_QKV) q4[r] = uv;
          ((u16*)C)[idx] = uv;
        } else if (EPI == EPI_F32)
          ((float*)C)[idx] = v;
        else
          ((float*)C)[idx] += v;
      }
      if constexpr (EPI == EPI_QKV) {
        if (col >= 2 * DD) {
          const int rbase = row0 + (mi << 4);
          const int bb = rbase >> 10, t = rbase & (TT - 1);
          const int hd = col - 2 * DD;
          u16* vp = Vt + ((size_t)(bb << 4) * 64 + (size_t)hd) * TT + t;
          *(ushort4*)vp = *(const ushort4*)q4;
        }
      }
    }
  }
}

// ======= head GEMM: 256^2 BK=64, 8-phase (4 phases/K-step, 2 dbuf) — r9 proven =======
template <int KDIM>
__global__ __launch_bounds__(512) void gemm256p_k(
    const u16* __restrict__ A, int lda,
    const u16* __restrict__ Bt, int ldb,
    float* __restrict__ C, int ldc, int mm) {
  extern __shared__ u16 smem[];   // 128 KiB

  const int nwg = gridDim.x;
  const int q = nwg >> 3, r = nwg & 7;
  const int xcd = blockIdx.x & 7, loc = blockIdx.x >> 3;
  const int wg = (xcd < r) ? (xcd * (q + 1) + loc) : (r * (q + 1) + (xcd - r) * q + loc);
  const int m0 = (wg % mm) << 8;
  const int n0 = (wg / mm) << 8;

  const int tid = threadIdx.x;
  const int lane = tid & 63;
  const int w = tid >> 6;
  const int wr = w >> 2, wc = w & 3;
  const int l = lane & 15, kq = lane >> 4;

  f32x4 acc[8][4];
#pragma unroll
  for (int i = 0; i < 8; ++i)
#pragma unroll
    for (int j = 0; j < 4; ++j) acc[i][j] = (f32x4){0.f, 0.f, 0.f, 0.f};

  auto STAGEH = [&](const u16* M, int ld, int base0, int tau, int isB, int h) {
    u16* dst = smem + (((((tau & 1) << 2) | (isB << 1) | h)) << 13);
    const int k0 = tau << 6;
#pragma unroll
    for (int cc = 0; cc < 2; ++cc) {
      const int c = tid + (cc << 9);
      const int row = c >> 3;
      const int s = (c & 7) ^ (row & 7);
      gl16(M + (size_t)(base0 + (h << 7) + row) * ld + k0 + (s << 3), dst + (c << 3));
    }
  };

  auto RD_A = [&](int d, int mi, int kk) -> bf16x8 {
    const int row = (mi << 4) + l;
    const u16* p = smem + (((d << 2) | wr) << 13);
    const int s = ((kk << 2) + kq) ^ (row & 7);
    return *(const bf16x8*)&p[(row << 6) + (s << 3)];
  };
  auto RD_B = [&](int d, int ni, int kk) -> bf16x8 {
    const int row = ((wc & 1) << 6) + (ni << 4) + l;
    const u16* p = smem + (((d << 2) | 2 | (wc >> 1)) << 13);
    const int s = ((kk << 2) + kq) ^ (row & 7);
    return *(const bf16x8*)&p[(row << 6) + (s << 3)];
  };

  constexpr int NT = KDIM >> 6;

  STAGEH(Bt, ldb, n0, 0, 1, 0); STAGEH(Bt, ldb, n0, 0, 1, 1);
  STAGEH(A,  lda, m0, 0, 0, 0); STAGEH(A,  lda, m0, 0, 0, 1);
  STAGEH(Bt, ldb, n0, 1, 1, 0); STAGEH(Bt, ldb, n0, 1, 1, 1);
  vwait<4>();
  __builtin_amdgcn_s_barrier();
  __builtin_amdgcn_sched_barrier(0);

#define PHASE_MFMA(Q)                                                                   \
  asm volatile("s_waitcnt lgkmcnt(0)" ::: "memory");                                    \
  __builtin_amdgcn_sched_barrier(0);                                                    \
  __builtin_amdgcn_s_setprio(1);                                                        \
  _Pragma("unroll")                                                                     \
  for (int kk = 0; kk < 2; ++kk)                                                        \
    _Pragma("unroll")                                                                   \
    for (int dm = 0; dm < 2; ++dm)                                                      \
      _Pragma("unroll")                                                                 \
      for (int ni = 0; ni < 4; ++ni)                                                    \
        acc[2 * (Q) + dm][ni] = __builtin_amdgcn_mfma_f32_16x16x32_bf16(                \
            af[dm][kk], bfr[ni][kk], acc[2 * (Q) + dm][ni], 0, 0, 0);                   \
  __builtin_amdgcn_s_setprio(0);                                                        \
  __builtin_amdgcn_sched_barrier(0);

#pragma unroll 1
  for (int t = 0; t < NT; ++t) {
    const int d = t & 1;
    bf16x8 bfr[4][2], af[2][2];

#pragma unroll
    for (int ni = 0; ni < 4; ++ni) {
      bfr[ni][0] = RD_B(d, ni, 0);
      bfr[ni][1] = RD_B(d, ni, 1);
    }
    af[0][0] = RD_A(d, 0, 0); af[0][1] = RD_A(d, 0, 1);
    af[1][0] = RD_A(d, 1, 0); af[1][1] = RD_A(d, 1, 1);
    if (t + 1 < NT) { STAGEH(A, lda, m0, t + 1, 0, 0); STAGEH(A, lda, m0, t + 1, 0, 1); }
    __builtin_amdgcn_sched_barrier(0);
    __builtin_amdgcn_s_barrier();
    PHASE_MFMA(0)
    __builtin_amdgcn_s_barrier();

    af[0][0] = RD_A(d, 2, 0); af[0][1] = RD_A(d, 2, 1);
    af[1][0] = RD_A(d, 3, 0); af[1][1] = RD_A(d, 3, 1);
    if (t + 2 < NT) STAGEH(Bt, ldb, n0, t + 2, 1, 0);
    __builtin_amdgcn_sched_barrier(0);
    __builtin_amdgcn_s_barrier();
    PHASE_MFMA(1)
    __builtin_amdgcn_s_barrier();

    af[0][0] = RD_A(d, 4, 0); af[0][1] = RD_A(d, 4, 1);
    af[1][0] = RD_A(d, 5, 0); af[1][1] = RD_A(d, 5, 1);
    if (t + 2 < NT) STAGEH(Bt, ldb, n0, t + 2, 1, 1);
    __builtin_amdgcn_sched_barrier(0);
    __builtin_amdgcn_s_barrier();
    PHASE_MFMA(2)
    __builtin_amdgcn_s_barrier();

    af[0][0] = RD_A(d, 6, 0); af[0][1] = RD_A(d, 6, 1);
    af[1][0] = RD_A(d, 7, 0); af[1][1] = RD_A(d, 7, 1);
    __builtin_amdgcn_sched_barrier(0);
    __builtin_amdgcn_s_barrier();
    PHASE_MFMA(3)
    if (t + 2 < NT) vwait<4>();
    else vwait<0>();
    __builtin_amdgcn_sched_barrier(0);
    __builtin_amdgcn_s_barrier();
  }
#undef PHASE_MFMA

  const int row0 = m0 + (wr << 7) + (kq << 2);
  const int col0 = n0 + (wc << 6) + l;
#pragma unroll
  for (int ni = 0; ni < 4; ++ni) {
    const int col = col0 + (ni << 4);
#pragma unroll
    for (int mi = 0; mi < 8; ++mi) {
#pragma unroll
      for (int r = 0; r < 4; ++r) {
        const int row = row0 + (mi << 4) + r;
        C[(size_t)row * ldc + col] = acc[mi][ni][r];
      }
    }
  }
}

extern "C" void kernel_launch(void* const* d_in, const int* in_sizes, int n_in,
                              void* d_out, int out_size, void* d_ws, size_t ws_size,
                              hipStream_t stream) {
  const int* tokens = (const int*)d_in[0];
  const float* emb_W = (const float*)d_in[1];
  const float* pos_W = (const float*)d_in[2];
  const float* g1 = (const float*)d_in[3];
  const float* be1 = (const float*)d_in[4];
  const float* Wqkv = (const float*)d_in[5];
  const float* bqkv = (const float*)d_in[6];
  const float* Wo = (const float*)d_in[7];
  const float* bo = (const float*)d_in[8];
  const float* g2 = (const float*)d_in[9];
  const float* be2 = (const float*)d_in[10];
  const float* Wf1 = (const float*)d_in[11];
  const float* bf1 = (const float*)d_in[12];
  const float* Wf2 = (const float*)d_in[13];
  const float* bf2 = (const float*)d_in[14];
  const float* gf = (const float*)d_in[15];
  const float* bef = (const float*)d_in[16];

  char* w = (char*)d_ws;
  auto alloc = [&](size_t bytes) {
    char* p = w;
    w += (bytes + 255) & ~(size_t)255;
    return p;
  };
  u16* WqkvT = (u16*)alloc((size_t)LL * TD3 * DD * 2);
  u16* WoT   = (u16*)alloc((size_t)LL * DD * DD * 2);
  u16* Wf1T  = (u16*)alloc((size_t)LL * FFF * DD * 2);
  u16* Wf2T  = (u16*)alloc((size_t)LL * DD * FFF * 2);
  u16* embB  = (u16*)alloc((size_t)VV * DD * 2);
  float* x   = (float*)alloc((size_t)MM * DD * 4);
  u16* h     = (u16*)alloc((size_t)MM * DD * 2);
  u16* qkv   = (u16*)alloc((size_t)MM * TD3 * 2);
  u16* Vt    = (u16*)alloc((size_t)32 * 64 * TT * 2);
  u16* o     = (u16*)alloc((size_t)MM * DD * 2);
  u16* h1    = (u16*)alloc((size_t)MM * FFF * 2);
  float* pp  = (float*)alloc((size_t)4 * MM * DD * 4);   // split-K partials

  bool big =
      hipFuncSetAttribute((const void*)&gemm256p_k<1024>,
                          hipFuncAttributeMaxDynamicSharedMemorySize, 131072) == hipSuccess;

  dim3 tb2(64, 4);
  transpose_cvt_k<<<dim3(TD3 / 64, DD / 32, LL), tb2, 0, stream>>>(Wqkv, WqkvT, DD, TD3);
  transpose_cvt_k<<<dim3(DD / 64, DD / 32, LL), tb2, 0, stream>>>(Wo, WoT, DD, DD);
  transpose_cvt_k<<<dim3(FFF / 64, DD / 32, LL), tb2, 0, stream>>>(Wf1, Wf1T, DD, FFF);
  transpose_cvt_k<<<dim3(DD / 64, FFF / 32, LL), tb2, 0, stream>>>(Wf2, Wf2T, FFF, DD);
  cvt_bf16_k<<<(VV * DD / 4) / 256, 256, 0, stream>>>(emb_W, embB, (long)VV * DD / 4);
  embed_k<<<MM, 256, 0, stream>>>(tokens, emb_W, pos_W, x);
  rmsnorm_k<<<MM, 256, 0, stream>>>(x, g1, be1, h);   // layer 0 pre-norm

  for (int i = 0; i < LL; ++i) {
    // --- attention sub-block (h = rmsnorm output already) ---
    gemm_bt3s<EPI_QKV><<<dim3(16, 24, 1), 256, 0, stream>>>(
        h, 0, 0, DD, WqkvT + (size_t)i * TD3 * DD, 0, 0, DD,
        qkv, 0, 0, TD3, bqkv + i * TD3, TD3, DD, Vt);
    flash4_k<<<dim3(32, 16), 256, 0, stream>>>(qkv, Vt, o);
    gemm_bt3s<EPI_F32><<<dim3(16, 8, 2), 256, 0, stream>>>(
        o, 0, 512, DD, WoT + (size_t)i * DD * DD, 0, 512, DD,
        pp, 0, (long)MM * DD, DD, nullptr, DD, 512, nullptr);
    addres_rms_k<2><<<MM, 256, 0, stream>>>(x, pp, bo + i * DD, g2 + i * DD, be2 + i * DD, h);
    // --- FFN sub-block ---
    gemm_bt3s<EPI_SELU><<<dim3(16, 32, 1), 256, 0, stream>>>(
        h, 0, 0, DD, Wf1T + (size_t)i * FFF * DD, 0, 0, DD,
        h1, 0, 0, FFF, bf1 + i * FFF, FFF, DD, nullptr);
    gemm_bt3s<EPI_F32><<<dim3(16, 8, 4), 256, 0, stream>>>(
        h1, 0, 1024, FFF, Wf2T + (size_t)i * DD * FFF, 0, 1024, FFF,
        pp, 0, (long)MM * DD, DD, nullptr, DD, 1024, nullptr);
    const bool last = (i == LL - 1);
    addres_rms_k<4><<<MM, 256, 0, stream>>>(
        x, pp, bf2 + i * DD,
        last ? gf : g1 + (i + 1) * DD, last ? bef : be1 + (i + 1) * DD, h);
  }

  // --- head: tied-embedding logits (h holds final-normed activations) ---
  if (big) {
    gemm256p_k<1024><<<1000, 512, 131072, stream>>>(
        h, DD, embB, DD, (float*)d_out, VV, 8);
  } else {
    gemm_bt<EPI_F32><<<dim3(16, 250, 1), 256, 0, stream>>>(
        h, 0, 0, DD, embB, 0, 0, DD,
        (float*)d_out, 0, 0, VV, nullptr, VV, DD);
  }
}

// Round 15
// 902.400 us; speedup vs baseline: 1.0183x; 1.0183x over previous
//
#include <hip/hip_runtime.h>

typedef unsigned short u16;
typedef __attribute__((ext_vector_type(8))) short bf16x8;
typedef __attribute__((ext_vector_type(4))) float f32x4;

#define DD 1024
#define TT 1024
#define NHH 16
#define VV 32000
#define FFF 4096
#define LL 4
#define MM 2048   // B*T
#define TD3 3072

__device__ __forceinline__ u16 f2bfu(float f) {
  unsigned int x = __builtin_bit_cast(unsigned int, f);
  return (u16)((x + 0x7FFFu + ((x >> 16) & 1u)) >> 16);
}

__device__ __forceinline__ void gl16(const u16* g, u16* l) {
  __builtin_amdgcn_global_load_lds((const __attribute__((address_space(1))) void*)g,
                                   (__attribute__((address_space(3))) void*)l, 16, 0, 0);
}

template <int N>
__device__ __forceinline__ void vwait() {
  if constexpr (N == 0) asm volatile("s_waitcnt vmcnt(0)" ::: "memory");
  else if constexpr (N == 4) asm volatile("s_waitcnt vmcnt(4)" ::: "memory");
  else asm volatile("s_waitcnt vmcnt(6)" ::: "memory");
}

// ------- weight transpose + f32->bf16 (16B vectorized stores) -------
__global__ void transpose_cvt_k(const float* __restrict__ in, u16* __restrict__ out,
                                int K, int N) {
  const size_t mat = (size_t)K * N;
  in += (size_t)blockIdx.z * mat;
  out += (size_t)blockIdx.z * mat;
  __shared__ float tile[32][65];
  const int n0 = blockIdx.x << 6, k0 = blockIdx.y << 5;
  const int tx = threadIdx.x, ty = threadIdx.y;
#pragma unroll
  for (int i = 0; i < 8; ++i)
    tile[(ty << 3) + i][tx] = in[(size_t)(k0 + (ty << 3) + i) * N + n0 + tx];
  __syncthreads();
  const int tid = (ty << 6) + tx;
  const int n = tid >> 2, oct = (tid & 3) << 3;
  union { u16 s[8]; uint4 u[1]; } tmp;
#pragma unroll
  for (int j = 0; j < 8; ++j) tmp.s[j] = f2bfu(tile[oct + j][n]);
  *(uint4*)(out + (size_t)(n0 + n) * K + k0 + oct) = tmp.u[0];
}

// ---------------- f32 -> bf16 elementwise (vec4) ----------------
__global__ void cvt_bf16_k(const float* __restrict__ in, u16* __restrict__ out, long n4) {
  const long i = (long)blockIdx.x * blockDim.x + threadIdx.x;
  if (i >= n4) return;
  const float4 v = ((const float4*)in)[i];
  ushort4 o;
  o.x = f2bfu(v.x); o.y = f2bfu(v.y); o.z = f2bfu(v.z); o.w = f2bfu(v.w);
  ((ushort4*)out)[i] = o;
}

// ---------------- embedding + positional ----------------
__global__ void embed_k(const int* __restrict__ tok, const float* __restrict__ emb,
                        const float* __restrict__ pos, float* __restrict__ x) {
  const int m = blockIdx.x, tid = threadIdx.x;
  const int t = m & (TT - 1);
  const int id = tok[m];
  const float4 e = ((const float4*)(emb + (size_t)id * DD))[tid];
  const float4 p = ((const float4*)(pos + (size_t)t * DD))[tid];
  float4 r;
  r.x = e.x + p.x; r.y = e.y + p.y; r.z = e.z + p.z; r.w = e.w + p.w;
  ((float4*)(x + (size_t)m * DD))[tid] = r;
}

// ---------------- RMSNorm (f32 in -> bf16 out) ----------------
__global__ void rmsnorm_k(const float* __restrict__ x, const float* __restrict__ g,
                          const float* __restrict__ be, u16* __restrict__ out) {
  const int row = blockIdx.x, tid = threadIdx.x;
  const float4 xv = ((const float4*)(x + (size_t)row * DD))[tid];
  float ss = xv.x * xv.x + xv.y * xv.y + xv.z * xv.z + xv.w * xv.w;
#pragma unroll
  for (int o = 32; o; o >>= 1) ss += __shfl_xor(ss, o);
  __shared__ float sm[4];
  if ((tid & 63) == 0) sm[tid >> 6] = ss;
  __syncthreads();
  const float tot = sm[0] + sm[1] + sm[2] + sm[3];
  const float rs = rsqrtf(tot * (1.f / DD) + 1e-6f);
  const float4 gv = ((const float4*)g)[tid];
  const float4 bv = ((const float4*)be)[tid];
  ushort4 o4;
  o4.x = f2bfu(xv.x * rs * gv.x + bv.x);
  o4.y = f2bfu(xv.y * rs * gv.y + bv.y);
  o4.z = f2bfu(xv.z * rs * gv.z + bv.z);
  o4.w = f2bfu(xv.w * rs * gv.w + bv.w);
  ((ushort4*)(out + (size_t)row * DD))[tid] = o4;
}

// ------- fused: x += sum(partials)+bias, then RMSNorm(x) -> bf16 out -------
template <int NP>
__global__ void addres_rms_k(float* __restrict__ x, const float* __restrict__ pp,
                             const float* __restrict__ bias, const float* __restrict__ g,
                             const float* __restrict__ be, u16* __restrict__ out) {
  const int row = blockIdx.x, tid = threadIdx.x;
  const size_t base = (size_t)row * (DD / 4) + tid;
  float4 s = ((float4*)x)[base];
  const float4 bv = ((const float4*)bias)[tid];
  s.x += bv.x; s.y += bv.y; s.z += bv.z; s.w += bv.w;
#pragma unroll
  for (int p = 0; p < NP; ++p) {
    const float4 pv = ((const float4*)pp)[(size_t)p * (MM * DD / 4) + base];
    s.x += pv.x; s.y += pv.y; s.z += pv.z; s.w += pv.w;
  }
  ((float4*)x)[base] = s;
  float ss = s.x * s.x + s.y * s.y + s.z * s.z + s.w * s.w;
#pragma unroll
  for (int o = 32; o; o >>= 1) ss += __shfl_xor(ss, o);
  __shared__ float sm[4];
  if ((tid & 63) == 0) sm[tid >> 6] = ss;
  __syncthreads();
  const float tot = sm[0] + sm[1] + sm[2] + sm[3];
  const float rs = rsqrtf(tot * (1.f / DD) + 1e-6f);
  const float4 gv = ((const float4*)g)[tid];
  const float4 bev = ((const float4*)be)[tid];
  ushort4 o4;
  o4.x = f2bfu(s.x * rs * gv.x + bev.x);
  o4.y = f2bfu(s.y * rs * gv.y + bev.y);
  o4.z = f2bfu(s.z * rs * gv.z + bev.z);
  o4.w = f2bfu(s.w * rs * gv.w + bev.w);
  ((ushort4*)(out + (size_t)row * DD))[tid] = o4;
}

// ======= flash attention, 8-wave wave-split (r13 proven) + Q-in-registers =======
// waves 0-3: qa=pair, waves 4-7: qa=15-pair; K/V tiles SHARED. Q held in regs
// (lane-private 2x16B fragments) -> LDS 64 KiB: K 16K | V 16K | P 32K.
__global__ __launch_bounds__(512) void flash8_k(const u16* __restrict__ qkv,
                                                const u16* __restrict__ Vt,
                                                u16* __restrict__ o) {
  extern __shared__ u16 sm8[];
  u16* Ks = sm8;             // [128*64] shared
  u16* Vs = sm8 + 8192;      // [64*128] shared
  u16* Ps = sm8 + 16384;     // [128*128] per-wave 16-row regions

  const int z = blockIdx.x;
  const int pair = blockIdx.y;
  const int b = z >> 4, h = z & 15;
  const int tid = threadIdx.x;
  const int lane = tid & 63;
  const int w = tid >> 6;        // 0..7
  const int hf = w >> 2;         // half
  const int wl = w & 3;          // wave-in-half

  const int qa = hf ? (15 - pair) : pair;
  const int q0 = qa << 6;
  const int nkt = (qa >> 1) + 1;
  const int nktmax = ((15 - pair) >> 1) + 1;

  const u16* qbase = qkv + (size_t)b * TT * TD3;
  const int kcb = (lane >> 4) << 4;

  // Q fragments in registers: lane-private rows, d = ks*32 + (lane>>4)*8 .. +7
  const int qrow = (wl << 4) + (lane & 15);
  bf16x8 aq[2];
#pragma unroll
  for (int ks = 0; ks < 2; ++ks)
    aq[ks] = *(const bf16x8*)(qbase + (long)(q0 + qrow) * TD3 + h * 64 +
                              ks * 32 + ((lane >> 4) << 3));

  float m_r[4], l_r[4];
  f32x4 oacc[4];
#pragma unroll
  for (int r = 0; r < 4; ++r) { m_r[r] = -1e30f; l_r[r] = 0.f; }
#pragma unroll
  for (int nd = 0; nd < 4; ++nd) oacc[nd] = (f32x4){0.f, 0.f, 0.f, 0.f};

  for (int kt = 0; kt < nktmax; ++kt) {
    const int t0 = kt << 7;
    // stage shared K tile [128][64] — all 8 waves
#pragma unroll
    for (int c = 0; c < 2; ++c) {
      const int rbase = c * 64 + w * 8;
      const int row = rbase + (lane >> 3);
      const u16* src = qbase + (long)(t0 + row) * TD3 + DD + h * 64 +
                       ((((lane & 7) << 4) ^ ((row & 7) << 4)) >> 1);
      gl16(src, &Ks[rbase * 64]);
    }
    // stage shared V tile [64 d][128 t] — all 8 waves
#pragma unroll
    for (int c = 0; c < 2; ++c) {
      const int rbase = c * 32 + w * 4;
      const int d = rbase + (lane >> 4);
      const u16* src = Vt + ((long)(z * 64 + d)) * TT + t0 +
                       ((((lane & 15) << 4) ^ ((d & 7) << 4)) >> 1);
      gl16(src, &Vs[rbase * 128]);
    }
    __syncthreads();

    if (kt < nkt) {
      f32x4 sacc[8];
#pragma unroll
      for (int ni = 0; ni < 8; ++ni) sacc[ni] = (f32x4){0.f, 0.f, 0.f, 0.f};
#pragma unroll
      for (int ks = 0; ks < 2; ++ks) {
#pragma unroll
        for (int ni = 0; ni < 8; ++ni) {
          const int key = (lane & 15) + (ni << 4);
          const bf16x8 bk = *(const bf16x8*)&Ks[key * 64 + (((ks * 64 + kcb) ^ ((key & 7) << 4)) >> 1)];
          sacc[ni] = __builtin_amdgcn_mfma_f32_16x16x32_bf16(aq[ks], bk, sacc[ni], 0, 0, 0);
        }
      }

      float mx[4] = {-1e30f, -1e30f, -1e30f, -1e30f};
      const bool diag = (kt == nkt - 1);
#pragma unroll
      for (int ni = 0; ni < 8; ++ni)
#pragma unroll
        for (int r = 0; r < 4; ++r) {
          float v = sacc[ni][r] * 0.125f;
          if (diag) {
            const int key = t0 + (lane & 15) + (ni << 4);
            const int qq = q0 + (wl << 4) + ((lane >> 4) << 2) + r;
            if (key > qq) v = -1e30f;
          }
          sacc[ni][r] = v;
          mx[r] = fmaxf(mx[r], v);
        }
#pragma unroll
      for (int st = 1; st < 16; st <<= 1)
#pragma unroll
        for (int r = 0; r < 4; ++r) mx[r] = fmaxf(mx[r], __shfl_xor(mx[r], st));
      float sc[4], sum[4];
#pragma unroll
      for (int r = 0; r < 4; ++r) {
        const float mn = fmaxf(m_r[r], mx[r]);
        sc[r] = __expf(m_r[r] - mn);
        m_r[r] = mn;
        sum[r] = 0.f;
      }
#pragma unroll
      for (int ni = 0; ni < 8; ++ni)
#pragma unroll
        for (int r = 0; r < 4; ++r) {
          const float e = __expf(sacc[ni][r] - m_r[r]);
          sum[r] += e;
          const int prow = (w << 4) + ((lane >> 4) << 2) + r;
          const int pcol = (lane & 15) + (ni << 4);
          Ps[prow * 128 + (((pcol << 1) ^ ((prow & 7) << 4)) >> 1)] = f2bfu(e);
        }
#pragma unroll
      for (int st = 1; st < 16; st <<= 1)
#pragma unroll
        for (int r = 0; r < 4; ++r) sum[r] += __shfl_xor(sum[r], st);
#pragma unroll
      for (int r = 0; r < 4; ++r) l_r[r] = l_r[r] * sc[r] + sum[r];
#pragma unroll
      for (int nd = 0; nd < 4; ++nd)
#pragma unroll
        for (int r = 0; r < 4; ++r) oacc[nd][r] *= sc[r];

#pragma unroll
      for (int ks2 = 0; ks2 < 4; ++ks2) {
        const int prow = (w << 4) + (lane & 15);
        const bf16x8 pa = *(const bf16x8*)&Ps[prow * 128 + (((ks2 * 64 + kcb) ^ ((prow & 7) << 4)) >> 1)];
#pragma unroll
        for (int nd = 0; nd < 4; ++nd) {
          const int dd2 = (lane & 15) + (nd << 4);
          const bf16x8 vb = *(const bf16x8*)&Vs[dd2 * 128 + (((ks2 * 64 + kcb) ^ ((dd2 & 7) << 4)) >> 1)];
          oacc[nd] = __builtin_amdgcn_mfma_f32_16x16x32_bf16(pa, vb, oacc[nd], 0, 0, 0);
        }
      }
    }
    __syncthreads();
  }

  float inv[4];
#pragma unroll
  for (int r = 0; r < 4; ++r) inv[r] = 1.f / l_r[r];
#pragma unroll
  for (int nd = 0; nd < 4; ++nd)
#pragma unroll
    for (int r = 0; r < 4; ++r) {
      const int row = q0 + (wl << 4) + ((lane >> 4) << 2) + r;
      const int col = (h << 6) + (lane & 15) + (nd << 4);
      o[(long)(b * TT + row) * DD + col] = f2bfu(oacc[nd][r] * inv[r]);
    }
}

// ---------------- flash attention (proven r2; fallback) ----------------
__global__ __launch_bounds__(256) void flash_k(const u16* __restrict__ qkv,
                                               const u16* __restrict__ Vt,
                                               u16* __restrict__ o) {
  const int z = blockIdx.x;
  const int pair = blockIdx.y;
  const int b = z >> 4, h = z & 15;
  const int tid = threadIdx.x;
  const int lane = tid & 63;
  const int w = tid >> 6;

  __shared__ u16 Qs[64 * 64];
  __shared__ u16 Ks[128 * 64];
  __shared__ u16 Vs[64 * 128];
  __shared__ u16 Ps[64 * 128];

  const u16* qbase = qkv + (size_t)b * TT * TD3;
  const int kcb = (lane >> 4) << 4;

  for (int half = 0; half < 2; ++half) {
    const int qa = half ? (15 - pair) : pair;
    const int q0 = qa << 6;
    const int nkt = (qa >> 1) + 1;

#pragma unroll
    for (int c = 0; c < 2; ++c) {
      const int rbase = c * 32 + w * 8;
      const int row = rbase + (lane >> 3);
      const u16* src = qbase + (long)(q0 + row) * TD3 + h * 64 +
                       ((((lane & 7) << 4) ^ ((row & 7) << 4)) >> 1);
      gl16(src, &Qs[rbase * 64]);
    }

    float m_r[4], l_r[4];
    f32x4 oacc[4];
#pragma unroll
    for (int r = 0; r < 4; ++r) { m_r[r] = -1e30f; l_r[r] = 0.f; }
#pragma unroll
    for (int nd = 0; nd < 4; ++nd) oacc[nd] = (f32x4){0.f, 0.f, 0.f, 0.f};

    for (int kt = 0; kt < nkt; ++kt) {
      const int t0 = kt << 7;
#pragma unroll
      for (int c = 0; c < 4; ++c) {
        const int rbase = c * 32 + w * 8;
        const int row = rbase + (lane >> 3);
        const u16* src = qbase + (long)(t0 + row) * TD3 + DD + h * 64 +
                         ((((lane & 7) << 4) ^ ((row & 7) << 4)) >> 1);
        gl16(src, &Ks[rbase * 64]);
      }
#pragma unroll
      for (int c = 0; c < 4; ++c) {
        const int rbase = c * 16 + w * 4;
        const int d = rbase + (lane >> 4);
        const u16* src = Vt + ((long)(z * 64 + d)) * TT + t0 +
                         ((((lane & 15) << 4) ^ ((d & 7) << 4)) >> 1);
        gl16(src, &Vs[rbase * 128]);
      }
      __syncthreads();

      f32x4 sacc[8];
#pragma unroll
      for (int ni = 0; ni < 8; ++ni) sacc[ni] = (f32x4){0.f, 0.f, 0.f, 0.f};
      const int qrow = (w << 4) + (lane & 15);
#pragma unroll
      for (int ks = 0; ks < 2; ++ks) {
        const bf16x8 aq = *(const bf16x8*)&Qs[qrow * 64 + (((ks * 64 + kcb) ^ ((qrow & 7) << 4)) >> 1)];
#pragma unroll
        for (int ni = 0; ni < 8; ++ni) {
          const int key = (lane & 15) + (ni << 4);
          const bf16x8 bk = *(const bf16x8*)&Ks[key * 64 + (((ks * 64 + kcb) ^ ((key & 7) << 4)) >> 1)];
          sacc[ni] = __builtin_amdgcn_mfma_f32_16x16x32_bf16(aq, bk, sacc[ni], 0, 0, 0);
        }
      }

      float mx[4] = {-1e30f, -1e30f, -1e30f, -1e30f};
      const bool diag = (kt == nkt - 1);
#pragma unroll
      for (int ni = 0; ni < 8; ++ni)
#pragma unroll
        for (int r = 0; r < 4; ++r) {
          float v = sacc[ni][r] * 0.125f;
          if (diag) {
            const int key = t0 + (lane & 15) + (ni << 4);
            const int qq = q0 + (w << 4) + ((lane >> 4) << 2) + r;
            if (key > qq) v = -1e30f;
          }
          sacc[ni][r] = v;
          mx[r] = fmaxf(mx[r], v);
        }
#pragma unroll
      for (int st = 1; st < 16; st <<= 1)
#pragma unroll
        for (int r = 0; r < 4; ++r) mx[r] = fmaxf(mx[r], __shfl_xor(mx[r], st));
      float sc[4], sum[4];
#pragma unroll
      for (int r = 0; r < 4; ++r) {
        const float mn = fmaxf(m_r[r], mx[r]);
        sc[r] = __expf(m_r[r] - mn);
        m_r[r] = mn;
        sum[r] = 0.f;
      }
#pragma unroll
      for (int ni = 0; ni < 8; ++ni)
#pragma unroll
        for (int r = 0; r < 4; ++r) {
          const float e = __expf(sacc[ni][r] - m_r[r]);
          sum[r] += e;
          const int prow = (w << 4) + ((lane >> 4) << 2) + r;
          const int pcol = (lane & 15) + (ni << 4);
          Ps[prow * 128 + (((pcol << 1) ^ ((prow & 7) << 4)) >> 1)] = f2bfu(e);
        }
#pragma unroll
      for (int st = 1; st < 16; st <<= 1)
#pragma unroll
        for (int r = 0; r < 4; ++r) sum[r] += __shfl_xor(sum[r], st);
#pragma unroll
      for (int r = 0; r < 4; ++r) l_r[r] = l_r[r] * sc[r] + sum[r];
#pragma unroll
      for (int nd = 0; nd < 4; ++nd)
#pragma unroll
        for (int r = 0; r < 4; ++r) oacc[nd][r] *= sc[r];

#pragma unroll
      for (int ks2 = 0; ks2 < 4; ++ks2) {
        const int prow = (w << 4) + (lane & 15);
        const bf16x8 pa = *(const bf16x8*)&Ps[prow * 128 + (((ks2 * 64 + kcb) ^ ((prow & 7) << 4)) >> 1)];
#pragma unroll
        for (int nd = 0; nd < 4; ++nd) {
          const int dd2 = (lane & 15) + (nd << 4);
          const bf16x8 vb = *(const bf16x8*)&Vs[dd2 * 128 + (((ks2 * 64 + kcb) ^ ((dd2 & 7) << 4)) >> 1)];
          oacc[nd] = __builtin_amdgcn_mfma_f32_16x16x32_bf16(pa, vb, oacc[nd], 0, 0, 0);
        }
      }
      __syncthreads();
    }

    float inv[4];
#pragma unroll
    for (int r = 0; r < 4; ++r) inv[r] = 1.f / l_r[r];
#pragma unroll
    for (int nd = 0; nd < 4; ++nd)
#pragma unroll
      for (int r = 0; r < 4; ++r) {
        const int row = q0 + (w << 4) + ((lane >> 4) << 2) + r;
        const int col = (h << 6) + (lane & 15) + (nd << 4);
        o[(long)(b * TT + row) * DD + col] = f2bfu(oacc[nd][r] * inv[r]);
      }
  }
}

// ---------------- generic batched GEMM (128^2, 2-phase; head fallback) ----------------
enum { EPI_BF16 = 0, EPI_BF16_BIAS = 1, EPI_SELU = 2, EPI_F32 = 3, EPI_RESID = 4, EPI_QKV = 5 };

template <int EPI>
__global__ __launch_bounds__(256) void gemm_bt(
    const u16* __restrict__ A, long az1, long az2, int lda,
    const u16* __restrict__ Bt, long bz1, long bz2, int ldb,
    void* __restrict__ C, long cz1, long cz2, int ldc,
    const float* __restrict__ bias, int Nvalid, int K) {
  const int z = blockIdx.z;
  A += (long)(z >> 4) * az1 + (long)(z & 15) * az2;
  Bt += (long)(z >> 4) * bz1 + (long)(z & 15) * bz2;
  const long coff = (long)(z >> 4) * cz1 + (long)(z & 15) * cz2;

  __shared__ u16 ldsA[2][128 * 32];
  __shared__ u16 ldsB[2][128 * 32];

  const int tid = threadIdx.x;
  const int lane = tid & 63;
  const int wave = tid >> 6;
  const int wr = wave >> 1, wc = wave & 1;
  const int m0 = blockIdx.x << 7, n0 = blockIdx.y << 7;

  f32x4 acc[4][4];
#pragma unroll
  for (int i = 0; i < 4; ++i)
#pragma unroll
    for (int j = 0; j < 4; ++j) acc[i][j] = (f32x4){0.f, 0.f, 0.f, 0.f};

  auto STAGE = [&](int buf, int kt) {
    const int k0 = kt << 5;
#pragma unroll
    for (int p = 0; p < 2; ++p) {
      const int c = tid + (p << 8);
      const int row = c >> 2, col = (c & 3) << 3;
      gl16(A + (long)(m0 + row) * lda + k0 + col, &ldsA[buf][c << 3]);
      gl16(Bt + (long)(n0 + row) * ldb + k0 + col, &ldsB[buf][c << 3]);
    }
  };

  const int nk = K >> 5;
  STAGE(0, 0);
  __syncthreads();
  int cur = 0;
  for (int kt = 0; kt < nk; ++kt) {
    if (kt + 1 < nk) STAGE(cur ^ 1, kt + 1);
    const int rb = lane & 15;
    const int kc = (lane >> 4) << 3;
    bf16x8 af[4], bfr[4];
#pragma unroll
    for (int mi = 0; mi < 4; ++mi)
      af[mi] = *(const bf16x8*)&ldsA[cur][(((wr << 6) + (mi << 4) + rb) << 5) + kc];
#pragma unroll
    for (int ni = 0; ni < 4; ++ni)
      bfr[ni] = *(const bf16x8*)&ldsB[cur][(((wc << 6) + (ni << 4) + rb) << 5) + kc];
#pragma unroll
    for (int mi = 0; mi < 4; ++mi)
#pragma unroll
      for (int ni = 0; ni < 4; ++ni)
        acc[mi][ni] = __builtin_amdgcn_mfma_f32_16x16x32_bf16(af[mi], bfr[ni], acc[mi][ni], 0, 0, 0);
    __syncthreads();
    cur ^= 1;
  }

  const int row0 = m0 + (wr << 6) + ((lane >> 4) << 2);
  const int col0 = n0 + (wc << 6) + (lane & 15);
#pragma unroll
  for (int ni = 0; ni < 4; ++ni) {
    const int col = col0 + (ni << 4);
    if (col >= Nvalid) continue;
    float bv = 0.f;
    if (EPI == EPI_BF16_BIAS || EPI == EPI_SELU || EPI == EPI_RESID) bv = bias[col];
#pragma unroll
    for (int mi = 0; mi < 4; ++mi) {
#pragma unroll
      for (int r = 0; r < 4; ++r) {
        const int row = row0 + (mi << 4) + r;
        const long idx = coff + (long)row * ldc + col;
        float v = acc[mi][ni][r] + bv;
        if (EPI == EPI_SELU)
          v = v > 0.f ? 1.0507009873554805f * v : 1.7580993408473766f * (__expf(v) - 1.f);
        if (EPI == EPI_BF16 || EPI == EPI_BF16_BIAS || EPI == EPI_SELU)
          ((u16*)C)[idx] = f2bfu(v);
        else if (EPI == EPI_F32)
          ((float*)C)[idx] = v;
        else
          ((float*)C)[idx] += v;
      }
    }
  }
}

// ------- gemm_bt3s: 128^2, 3-buffer ring, counted vmcnt(4), raw barriers, -------
// row-paired XOR-swizzled LDS. EPI_QKV scatters V third into Vt.
template <int EPI>
__global__ __launch_bounds__(256) void gemm_bt3s(
    const u16* __restrict__ A, long az1, long az2, int lda,
    const u16* __restrict__ Bt, long bz1, long bz2, int ldb,
    void* __restrict__ C, long cz1, long cz2, int ldc,
    const float* __restrict__ bias, int Nvalid, int K,
    u16* __restrict__ Vt) {
  const int z = blockIdx.z;
  A += (long)(z >> 4) * az1 + (long)(z & 15) * az2;
  Bt += (long)(z >> 4) * bz1 + (long)(z & 15) * bz2;
  const long coff = (long)(z >> 4) * cz1 + (long)(z & 15) * cz2;

  __shared__ u16 ldsA[3][128 * 32];
  __shared__ u16 ldsB[3][128 * 32];

  const int tid = threadIdx.x;
  const int lane = tid & 63;
  const int wave = tid >> 6;
  const int wr = wave >> 1, wc = wave & 1;
  const int m0 = blockIdx.x << 7, n0 = blockIdx.y << 7;

  f32x4 acc[4][4];
#pragma unroll
  for (int i = 0; i < 4; ++i)
#pragma unroll
    for (int j = 0; j < 4; ++j) acc[i][j] = (f32x4){0.f, 0.f, 0.f, 0.f};

  auto STAGE = [&](int buf, int kt) {
    const int k0 = kt << 5;
#pragma unroll
    for (int p = 0; p < 2; ++p) {
      const int c = tid + (p << 8);
      const int r2 = c >> 3, sp = c & 7;
      const int s = sp ^ (r2 & 7);
      const int row = r2 + ((s >> 2) << 6);
      const int col = k0 + ((s & 3) << 3);
      gl16(A + (long)(m0 + row) * lda + col, &ldsA[buf][c << 3]);
      gl16(Bt + (long)(n0 + row) * ldb + col, &ldsB[buf][c << 3]);
    }
  };

  const int nk = K >> 5;
  STAGE(0, 0);
  STAGE(1, 1);

  const int rb = lane & 15;
  const int kq = lane >> 4;
  int cur = 0, stg = 2;
#pragma unroll 1
  for (int kt = 0; kt < nk; ++kt) {
    if (kt + 1 < nk) vwait<4>();
    else vwait<0>();
    __builtin_amdgcn_s_barrier();
    __builtin_amdgcn_sched_barrier(0);

    bf16x8 af[4], bfr[4];
#pragma unroll
    for (int mi = 0; mi < 4; ++mi) {
      const int row = (wr << 6) + (mi << 4) + rb;
      const int r2 = row & 63;
      const int sp = (kq + ((row >> 6) << 2)) ^ (r2 & 7);
      af[mi] = *(const bf16x8*)&ldsA[cur][(r2 << 6) + (sp << 3)];
    }
#pragma unroll
    for (int ni = 0; ni < 4; ++ni) {
      const int row = (wc << 6) + (ni << 4) + rb;
      const int r2 = row & 63;
      const int sp = (kq + ((row >> 6) << 2)) ^ (r2 & 7);
      bfr[ni] = *(const bf16x8*)&ldsB[cur][(r2 << 6) + (sp << 3)];
    }
    asm volatile("s_waitcnt lgkmcnt(0)" ::: "memory");
    __builtin_amdgcn_sched_barrier(0);
    __builtin_amdgcn_s_barrier();
    __builtin_amdgcn_sched_barrier(0);
    if (kt + 2 < nk) STAGE(stg, kt + 2);
    __builtin_amdgcn_sched_barrier(0);

    __builtin_amdgcn_s_setprio(1);
#pragma unroll
    for (int mi = 0; mi < 4; ++mi)
#pragma unroll
      for (int ni = 0; ni < 4; ++ni)
        acc[mi][ni] = __builtin_amdgcn_mfma_f32_16x16x32_bf16(af[mi], bfr[ni], acc[mi][ni], 0, 0, 0);
    __builtin_amdgcn_s_setprio(0);

    cur = (cur == 2) ? 0 : cur + 1;
    stg = (stg == 2) ? 0 : stg + 1;
  }

  const int row0 = m0 + (wr << 6) + ((lane >> 4) << 2);
  const int col0 = n0 + (wc << 6) + (lane & 15);
#pragma unroll
  for (int ni = 0; ni < 4; ++ni) {
    const int col = col0 + (ni << 4);
    if (col >= Nvalid) continue;
    float bv = 0.f;
    if (EPI == EPI_BF16_BIAS || EPI == EPI_SELU || EPI == EPI_RESID || EPI == EPI_QKV)
      bv = bias[col];
#pragma unroll
    for (int mi = 0; mi < 4; ++mi) {
      u16 q4[4];
#pragma unroll
      for (int r = 0; r < 4; ++r) {
        const int row = row0 + (mi << 4) + r;
        const long idx = coff + (long)row * ldc + col;
        float v = acc[mi][ni][r] + bv;
        if (EPI == EPI_SELU)
          v = v > 0.f ? 1.0507009873554805f * v : 1.7580993408473766f * (__expf(v) - 1.f);
        if (EPI == EPI_BF16 || EPI == EPI_BF16_BIAS || EPI == EPI_SELU || EPI == EPI_QKV) {
          const u16 uv = f2bfu(v);
          if (EPI == EPI_QKV) q4[r] = uv;
          ((u16*)C)[idx] = uv;
        } else if (EPI == EPI_F32)
          ((float*)C)[idx] = v;
        else
          ((float*)C)[idx] += v;
      }
      if constexpr (EPI == EPI_QKV) {
        if (col >= 2 * DD) {
          const int rbase = row0 + (mi << 4);
          const int bb = rbase >> 10, t = rbase & (TT - 1);
          const int hd = col - 2 * DD;
          u16* vp = Vt + ((size_t)(bb << 4) * 64 + (size_t)hd) * TT + t;
          *(ushort4*)vp = *(const ushort4*)q4;
        }
      }
    }
  }
}

// ======= head GEMM: 256^2 BK=64, 8-phase (4 phases/K-step, 2 dbuf) — r9 proven =======
template <int KDIM>
__global__ __launch_bounds__(512) void gemm256p_k(
    const u16* __restrict__ A, int lda,
    const u16* __restrict__ Bt, int ldb,
    float* __restrict__ C, int ldc, int mm) {
  extern __shared__ u16 smem[];   // 128 KiB

  const int nwg = gridDim.x;
  const int q = nwg >> 3, r = nwg & 7;
  const int xcd = blockIdx.x & 7, loc = blockIdx.x >> 3;
  const int wg = (xcd < r) ? (xcd * (q + 1) + loc) : (r * (q + 1) + (xcd - r) * q + loc);
  const int m0 = (wg % mm) << 8;
  const int n0 = (wg / mm) << 8;

  const int tid = threadIdx.x;
  const int lane = tid & 63;
  const int w = tid >> 6;
  const int wr = w >> 2, wc = w & 3;
  const int l = lane & 15, kq = lane >> 4;

  f32x4 acc[8][4];
#pragma unroll
  for (int i = 0; i < 8; ++i)
#pragma unroll
    for (int j = 0; j < 4; ++j) acc[i][j] = (f32x4){0.f, 0.f, 0.f, 0.f};

  auto STAGEH = [&](const u16* M, int ld, int base0, int tau, int isB, int h) {
    u16* dst = smem + (((((tau & 1) << 2) | (isB << 1) | h)) << 13);
    const int k0 = tau << 6;
#pragma unroll
    for (int cc = 0; cc < 2; ++cc) {
      const int c = tid + (cc << 9);
      const int row = c >> 3;
      const int s = (c & 7) ^ (row & 7);
      gl16(M + (size_t)(base0 + (h << 7) + row) * ld + k0 + (s << 3), dst + (c << 3));
    }
  };

  auto RD_A = [&](int d, int mi, int kk) -> bf16x8 {
    const int row = (mi << 4) + l;
    const u16* p = smem + (((d << 2) | wr) << 13);
    const int s = ((kk << 2) + kq) ^ (row & 7);
    return *(const bf16x8*)&p[(row << 6) + (s << 3)];
  };
  auto RD_B = [&](int d, int ni, int kk) -> bf16x8 {
    const int row = ((wc & 1) << 6) + (ni << 4) + l;
    const u16* p = smem + (((d << 2) | 2 | (wc >> 1)) << 13);
    const int s = ((kk << 2) + kq) ^ (row & 7);
    return *(const bf16x8*)&p[(row << 6) + (s << 3)];
  };

  constexpr int NT = KDIM >> 6;

  STAGEH(Bt, ldb, n0, 0, 1, 0); STAGEH(Bt, ldb, n0, 0, 1, 1);
  STAGEH(A,  lda, m0, 0, 0, 0); STAGEH(A,  lda, m0, 0, 0, 1);
  STAGEH(Bt, ldb, n0, 1, 1, 0); STAGEH(Bt, ldb, n0, 1, 1, 1);
  vwait<4>();
  __builtin_amdgcn_s_barrier();
  __builtin_amdgcn_sched_barrier(0);

#define PHASE_MFMA(Q)                                                                   \
  asm volatile("s_waitcnt lgkmcnt(0)" ::: "memory");                                    \
  __builtin_amdgcn_sched_barrier(0);                                                    \
  __builtin_amdgcn_s_setprio(1);                                                        \
  _Pragma("unroll")                                                                     \
  for (int kk = 0; kk < 2; ++kk)                                                        \
    _Pragma("unroll")                                                                   \
    for (int dm = 0; dm < 2; ++dm)                                                      \
      _Pragma("unroll")                                                                 \
      for (int ni = 0; ni < 4; ++ni)                                                    \
        acc[2 * (Q) + dm][ni] = __builtin_amdgcn_mfma_f32_16x16x32_bf16(                \
            af[dm][kk], bfr[ni][kk], acc[2 * (Q) + dm][ni], 0, 0, 0);                   \
  __builtin_amdgcn_s_setprio(0);                                                        \
  __builtin_amdgcn_sched_barrier(0);

#pragma unroll 1
  for (int t = 0; t < NT; ++t) {
    const int d = t & 1;
    bf16x8 bfr[4][2], af[2][2];

#pragma unroll
    for (int ni = 0; ni < 4; ++ni) {
      bfr[ni][0] = RD_B(d, ni, 0);
      bfr[ni][1] = RD_B(d, ni, 1);
    }
    af[0][0] = RD_A(d, 0, 0); af[0][1] = RD_A(d, 0, 1);
    af[1][0] = RD_A(d, 1, 0); af[1][1] = RD_A(d, 1, 1);
    if (t + 1 < NT) { STAGEH(A, lda, m0, t + 1, 0, 0); STAGEH(A, lda, m0, t + 1, 0, 1); }
    __builtin_amdgcn_sched_barrier(0);
    __builtin_amdgcn_s_barrier();
    PHASE_MFMA(0)
    __builtin_amdgcn_s_barrier();

    af[0][0] = RD_A(d, 2, 0); af[0][1] = RD_A(d, 2, 1);
    af[1][0] = RD_A(d, 3, 0); af[1][1] = RD_A(d, 3, 1);
    if (t + 2 < NT) STAGEH(Bt, ldb, n0, t + 2, 1, 0);
    __builtin_amdgcn_sched_barrier(0);
    __builtin_amdgcn_s_barrier();
    PHASE_MFMA(1)
    __builtin_amdgcn_s_barrier();

    af[0][0] = RD_A(d, 4, 0); af[0][1] = RD_A(d, 4, 1);
    af[1][0] = RD_A(d, 5, 0); af[1][1] = RD_A(d, 5, 1);
    if (t + 2 < NT) STAGEH(Bt, ldb, n0, t + 2, 1, 1);
    __builtin_amdgcn_sched_barrier(0);
    __builtin_amdgcn_s_barrier();
    PHASE_MFMA(2)
    __builtin_amdgcn_s_barrier();

    af[0][0] = RD_A(d, 6, 0); af[0][1] = RD_A(d, 6, 1);
    af[1][0] = RD_A(d, 7, 0); af[1][1] = RD_A(d, 7, 1);
    __builtin_amdgcn_sched_barrier(0);
    __builtin_amdgcn_s_barrier();
    PHASE_MFMA(3)
    if (t + 2 < NT) vwait<4>();
    else vwait<0>();
    __builtin_amdgcn_sched_barrier(0);
    __builtin_amdgcn_s_barrier();
  }
#undef PHASE_MFMA

  const int row0 = m0 + (wr << 7) + (kq << 2);
  const int col0 = n0 + (wc << 6) + l;
#pragma unroll
  for (int ni = 0; ni < 4; ++ni) {
    const int col = col0 + (ni << 4);
#pragma unroll
    for (int mi = 0; mi < 8; ++mi) {
#pragma unroll
      for (int r = 0; r < 4; ++r) {
        const int row = row0 + (mi << 4) + r;
        C[(size_t)row * ldc + col] = acc[mi][ni][r];
      }
    }
  }
}

extern "C" void kernel_launch(void* const* d_in, const int* in_sizes, int n_in,
                              void* d_out, int out_size, void* d_ws, size_t ws_size,
                              hipStream_t stream) {
  const int* tokens = (const int*)d_in[0];
  const float* emb_W = (const float*)d_in[1];
  const float* pos_W = (const float*)d_in[2];
  const float* g1 = (const float*)d_in[3];
  const float* be1 = (const float*)d_in[4];
  const float* Wqkv = (const float*)d_in[5];
  const float* bqkv = (const float*)d_in[6];
  const float* Wo = (const float*)d_in[7];
  const float* bo = (const float*)d_in[8];
  const float* g2 = (const float*)d_in[9];
  const float* be2 = (const float*)d_in[10];
  const float* Wf1 = (const float*)d_in[11];
  const float* bf1 = (const float*)d_in[12];
  const float* Wf2 = (const float*)d_in[13];
  const float* bf2 = (const float*)d_in[14];
  const float* gf = (const float*)d_in[15];
  const float* bef = (const float*)d_in[16];

  char* w = (char*)d_ws;
  auto alloc = [&](size_t bytes) {
    char* p = w;
    w += (bytes + 255) & ~(size_t)255;
    return p;
  };
  u16* WqkvT = (u16*)alloc((size_t)LL * TD3 * DD * 2);
  u16* WoT   = (u16*)alloc((size_t)LL * DD * DD * 2);
  u16* Wf1T  = (u16*)alloc((size_t)LL * FFF * DD * 2);
  u16* Wf2T  = (u16*)alloc((size_t)LL * DD * FFF * 2);
  u16* embB  = (u16*)alloc((size_t)VV * DD * 2);
  float* x   = (float*)alloc((size_t)MM * DD * 4);
  u16* h     = (u16*)alloc((size_t)MM * DD * 2);
  u16* qkv   = (u16*)alloc((size_t)MM * TD3 * 2);
  u16* Vt    = (u16*)alloc((size_t)32 * 64 * TT * 2);
  u16* o     = (u16*)alloc((size_t)MM * DD * 2);
  u16* h1    = (u16*)alloc((size_t)MM * FFF * 2);
  float* pp  = (float*)alloc((size_t)4 * MM * DD * 4);   // split-K partials

  bool big =
      hipFuncSetAttribute((const void*)&gemm256p_k<1024>,
                          hipFuncAttributeMaxDynamicSharedMemorySize, 131072) == hipSuccess;
  bool fl8 =
      hipFuncSetAttribute((const void*)&flash8_k,
                          hipFuncAttributeMaxDynamicSharedMemorySize, 65536) == hipSuccess;

  dim3 tb2(64, 4);
  transpose_cvt_k<<<dim3(TD3 / 64, DD / 32, LL), tb2, 0, stream>>>(Wqkv, WqkvT, DD, TD3);
  transpose_cvt_k<<<dim3(DD / 64, DD / 32, LL), tb2, 0, stream>>>(Wo, WoT, DD, DD);
  transpose_cvt_k<<<dim3(FFF / 64, DD / 32, LL), tb2, 0, stream>>>(Wf1, Wf1T, DD, FFF);
  transpose_cvt_k<<<dim3(DD / 64, FFF / 32, LL), tb2, 0, stream>>>(Wf2, Wf2T, FFF, DD);
  cvt_bf16_k<<<(VV * DD / 4) / 256, 256, 0, stream>>>(emb_W, embB, (long)VV * DD / 4);
  embed_k<<<MM, 256, 0, stream>>>(tokens, emb_W, pos_W, x);
  rmsnorm_k<<<MM, 256, 0, stream>>>(x, g1, be1, h);   // layer 0 pre-norm

  for (int i = 0; i < LL; ++i) {
    // --- attention sub-block (h = rmsnorm output already) ---
    gemm_bt3s<EPI_QKV><<<dim3(16, 24, 1), 256, 0, stream>>>(
        h, 0, 0, DD, WqkvT + (size_t)i * TD3 * DD, 0, 0, DD,
        qkv, 0, 0, TD3, bqkv + i * TD3, TD3, DD, Vt);
    if (fl8)
      flash8_k<<<dim3(32, 8), 512, 65536, stream>>>(qkv, Vt, o);
    else
      flash_k<<<dim3(32, 8), 256, 0, stream>>>(qkv, Vt, o);
    gemm_bt3s<EPI_F32><<<dim3(16, 8, 2), 256, 0, stream>>>(
        o, 0, 512, DD, WoT + (size_t)i * DD * DD, 0, 512, DD,
        pp, 0, (long)MM * DD, DD, nullptr, DD, 512, nullptr);
    addres_rms_k<2><<<MM, 256, 0, stream>>>(x, pp, bo + i * DD, g2 + i * DD, be2 + i * DD, h);
    // --- FFN sub-block ---
    gemm_bt3s<EPI_SELU><<<dim3(16, 32, 1), 256, 0, stream>>>(
        h, 0, 0, DD, Wf1T + (size_t)i * FFF * DD, 0, 0, DD,
        h1, 0, 0, FFF, bf1 + i * FFF, FFF, DD, nullptr);
    gemm_bt3s<EPI_F32><<<dim3(16, 8, 4), 256, 0, stream>>>(
        h1, 0, 1024, FFF, Wf2T + (size_t)i * DD * FFF, 0, 1024, FFF,
        pp, 0, (long)MM * DD, DD, nullptr, DD, 1024, nullptr);
    const bool last = (i == LL - 1);
    addres_rms_k<4><<<MM, 256, 0, stream>>>(
        x, pp, bf2 + i * DD,
        last ? gf : g1 + (i + 1) * DD, last ? bef : be1 + (i + 1) * DD, h);
  }

  // --- head: tied-embedding logits (h holds final-normed activations) ---
  if (big) {
    gemm256p_k<1024><<<1000, 512, 131072, stream>>>(
        h, DD, embB, DD, (float*)d_out, VV, 8);
  } else {
    gemm_bt<EPI_F32><<<dim3(16, 250, 1), 256, 0, stream>>>(
        h, 0, 0, DD, embB, 0, 0, DD,
        (float*)d_out, 0, 0, VV, nullptr, VV, DD);
  }
}